// Round 1
// baseline (1557.169 us; speedup 1.0000x reference)
//
#include <hip/hip_runtime.h>

#define N_NODES 50000
#define N_EDGES 1600000
#define HDIM 64
#define NLAYERS 3
#define NGRAPH 128
#define BN_EPS 1e-5f

// ---------------- scatter-add: agg[dst[e]][c] += h[src[e]][c] ----------------
__global__ __launch_bounds__(256) void scatter_kernel(
    const float* __restrict__ h, const int* __restrict__ src,
    const int* __restrict__ dst, float* __restrict__ agg)
{
    int e = blockIdx.x * 4 + (threadIdx.x >> 6);
    int c = threadIdx.x & 63;
    if (e >= N_EDGES) return;
    int s = src[e];
    int d = dst[e];
    atomicAdd(&agg[d * HDIM + c], h[s * HDIM + c]);
}

// ------------- z = (agg + hin) @ W1 + b1 ; accumulate BN stats ---------------
// z may alias agg (each row staged to LDS before the write-back).
__global__ __launch_bounds__(256) void gemm1_kernel(
    const float* __restrict__ agg, const float* __restrict__ hin,
    const float* __restrict__ W1, const float* __restrict__ b1,
    float* __restrict__ z, float* __restrict__ stats /* sum[64], sumsq[64] */)
{
    __shared__ float sW[HDIM * HDIM];
    __shared__ float sIn[4][HDIM];
    __shared__ float sRed[4][HDIM];
    int tid = threadIdx.x;
    for (int i = tid; i < HDIM * HDIM; i += 256) sW[i] = W1[i];
    int r = tid >> 6, c = tid & 63;
    float bias = b1[c];
    float s = 0.f, s2 = 0.f;
    int row0 = blockIdx.x * 64;
    __syncthreads();
    for (int it = 0; it < 16; ++it) {
        int row = row0 + it * 4 + r;
        if (row < N_NODES)
            sIn[r][c] = agg[row * HDIM + c] + hin[row * HDIM + c];
        __syncthreads();
        if (row < N_NODES) {
            float acc = bias;
            #pragma unroll
            for (int k = 0; k < HDIM; ++k)
                acc = fmaf(sIn[r][k], sW[k * HDIM + c], acc);
            z[row * HDIM + c] = acc;
            s += acc;
            s2 += acc * acc;
        }
        __syncthreads();
    }
    sRed[r][c] = s;
    __syncthreads();
    if (r == 0)
        atomicAdd(&stats[c], sRed[0][c] + sRed[1][c] + sRed[2][c] + sRed[3][c]);
    __syncthreads();
    sRed[r][c] = s2;
    __syncthreads();
    if (r == 0)
        atomicAdd(&stats[HDIM + c], sRed[0][c] + sRed[1][c] + sRed[2][c] + sRed[3][c]);
}

// -------- BN finalize: scale = gamma*rsqrt(var+eps); shift = beta-mu*scale ----
__global__ void bn_finalize(const float* __restrict__ stats,
                            const float* __restrict__ gamma,
                            const float* __restrict__ beta,
                            float* __restrict__ scsh)
{
    int c = threadIdx.x;
    float mu  = stats[c] / (float)N_NODES;
    float var = stats[HDIM + c] / (float)N_NODES - mu * mu;
    float sc  = gamma[c] * rsqrtf(var + BN_EPS);
    scsh[c] = sc;
    scsh[HDIM + c] = beta[c] - mu * sc;
}

// ------- hout = relu( relu(z*scale+shift) @ W2 + b2 )  (BN applied on read) ---
__global__ __launch_bounds__(256) void gemm2_kernel(
    const float* __restrict__ z, const float* __restrict__ W2,
    const float* __restrict__ b2, const float* __restrict__ scsh,
    float* __restrict__ hout)
{
    __shared__ float sW[HDIM * HDIM];
    __shared__ float sIn[4][HDIM];
    int tid = threadIdx.x;
    for (int i = tid; i < HDIM * HDIM; i += 256) sW[i] = W2[i];
    int r = tid >> 6, c = tid & 63;
    float sc = scsh[c], sh = scsh[HDIM + c];
    float bias = b2[c];
    int row0 = blockIdx.x * 64;
    __syncthreads();
    for (int it = 0; it < 16; ++it) {
        int row = row0 + it * 4 + r;
        if (row < N_NODES) {
            float v = z[row * HDIM + c] * sc + sh;
            sIn[r][c] = v > 0.f ? v : 0.f;
        }
        __syncthreads();
        if (row < N_NODES) {
            float acc = bias;
            #pragma unroll
            for (int k = 0; k < HDIM; ++k)
                acc = fmaf(sIn[r][k], sW[k * HDIM + c], acc);
            acc = acc > 0.f ? acc : 0.f;
            hout[row * HDIM + c] = acc;
        }
        __syncthreads();
    }
}

// ---------------- segment mean pool (accumulate) ------------------------------
__global__ __launch_bounds__(256) void pool_kernel(
    const float* __restrict__ h, const int* __restrict__ batch,
    float* __restrict__ pooled, float* __restrict__ cnt)
{
    int n = blockIdx.x * 4 + (threadIdx.x >> 6);
    int c = threadIdx.x & 63;
    if (n >= N_NODES) return;
    int g = batch[n];
    atomicAdd(&pooled[g * HDIM + c], h[n * HDIM + c]);
    if (c == 0) atomicAdd(&cnt[g], 1.0f);
}

// --------------- head: relu(mean @ Wh1 + bh1) @ Wh2 + bh2 ---------------------
__global__ __launch_bounds__(64) void head_kernel(
    const float* __restrict__ pooled, const float* __restrict__ cnt,
    const float* __restrict__ Wh1, const float* __restrict__ bh1,
    const float* __restrict__ Wh2, const float* __restrict__ bh2,
    float* __restrict__ out)
{
    __shared__ float sm[HDIM];
    int g = blockIdx.x;
    int c = threadIdx.x;
    float denom = fmaxf(cnt[g], 1.0f);
    sm[c] = pooled[g * HDIM + c] / denom;
    __syncthreads();
    float acc = bh1[c];
    #pragma unroll
    for (int k = 0; k < HDIM; ++k)
        acc = fmaf(sm[k], Wh1[k * HDIM + c], acc);
    acc = fmaxf(acc, 0.f);
    float p = acc * Wh2[c];
    for (int off = 32; off > 0; off >>= 1)
        p += __shfl_down(p, off, 64);
    if (c == 0) out[g] = p + bh2[0];
}

extern "C" void kernel_launch(void* const* d_in, const int* in_sizes, int n_in,
                              void* d_out, int out_size, void* d_ws, size_t ws_size,
                              hipStream_t stream)
{
    const float* x     = (const float*)d_in[0];
    const int*   ei    = (const int*)d_in[1];
    const int*   batch = (const int*)d_in[2];
    const float* W1    = (const float*)d_in[3];
    const float* b1    = (const float*)d_in[4];
    const float* gamma = (const float*)d_in[5];
    const float* beta  = (const float*)d_in[6];
    const float* W2    = (const float*)d_in[7];
    const float* b2    = (const float*)d_in[8];
    const float* Wh1   = (const float*)d_in[9];
    const float* bh1   = (const float*)d_in[10];
    const float* Wh2   = (const float*)d_in[11];
    const float* bh2   = (const float*)d_in[12];
    float* out = (float*)d_out;

    float* ws     = (float*)d_ws;
    float* h      = ws;                       // N*64
    float* agg    = h + (size_t)N_NODES * HDIM; // N*64 (also used as z)
    float* stats  = agg + (size_t)N_NODES * HDIM; // 128
    float* scsh   = stats + 2 * HDIM;         // 128
    float* pooled = scsh + 2 * HDIM;          // 128*64
    float* cnt    = pooled + NGRAPH * HDIM;   // 128

    const int* src = ei;
    const int* dst = ei + N_EDGES;

    int gemmGrid    = (N_NODES + 63) / 64;     // 782
    int scatterGrid = (N_EDGES + 3) / 4;       // 400000

    for (int l = 0; l < NLAYERS; ++l) {
        const float* hin = (l == 0) ? x : h;
        hipMemsetAsync(agg, 0, (size_t)N_NODES * HDIM * sizeof(float), stream);
        hipMemsetAsync(stats, 0, 2 * HDIM * sizeof(float), stream);
        scatter_kernel<<<scatterGrid, 256, 0, stream>>>(hin, src, dst, agg);
        gemm1_kernel<<<gemmGrid, 256, 0, stream>>>(agg, hin, W1 + l * HDIM * HDIM,
                                                   b1 + l * HDIM, agg, stats);
        bn_finalize<<<1, 64, 0, stream>>>(stats, gamma + l * HDIM, beta + l * HDIM, scsh);
        gemm2_kernel<<<gemmGrid, 256, 0, stream>>>(agg, W2 + l * HDIM * HDIM,
                                                   b2 + l * HDIM, scsh, h);
    }

    hipMemsetAsync(pooled, 0, (NGRAPH * HDIM + NGRAPH) * sizeof(float), stream);
    pool_kernel<<<(N_NODES + 3) / 4, 256, 0, stream>>>(h, batch, pooled, cnt);
    head_kernel<<<NGRAPH, 64, 0, stream>>>(pooled, cnt, Wh1, bh1, Wh2, bh2, out);
}

// Round 2
// 1009.641 us; speedup vs baseline: 1.5423x; 1.5423x over previous
//
#include <hip/hip_runtime.h>

#define N_NODES 50000
#define N_EDGES 1600000
#define HDIM 64
#define NLAYERS 3
#define NGRAPH 128
#define BN_EPS 1e-5f

// ---------------- degree histogram: deg[dst[e]]++ ----------------
__global__ __launch_bounds__(256) void hist_kernel(
    const int* __restrict__ dst, int* __restrict__ deg)
{
    int e = blockIdx.x * 256 + threadIdx.x;
    if (e < N_EDGES) atomicAdd(&deg[dst[e]], 1);
}

// ---------------- single-block exclusive scan of deg -> rowptr, cursor -------
__global__ __launch_bounds__(1024) void scan_kernel(
    const int* __restrict__ deg, int* __restrict__ rowptr, int* __restrict__ cursor)
{
    __shared__ int wsum[16];
    __shared__ int woff[17];
    int tid = threadIdx.x;
    int lane = tid & 63, wid = tid >> 6;
    int run = 0;  // persistent in tid 0's registers
    for (int base = 0; base < N_NODES; base += 1024) {
        int i = base + tid;
        int v = (i < N_NODES) ? deg[i] : 0;
        // inclusive scan within wave
        int incl = v;
        #pragma unroll
        for (int off = 1; off < 64; off <<= 1) {
            int t = __shfl_up(incl, off, 64);
            if (lane >= off) incl += t;
        }
        if (lane == 63) wsum[wid] = incl;
        __syncthreads();
        if (tid == 0) {
            int r = run;
            #pragma unroll
            for (int w = 0; w < 16; ++w) { woff[w] = r; r += wsum[w]; }
            woff[16] = r;
            run = r;
        }
        __syncthreads();
        if (i < N_NODES) {
            int excl = woff[wid] + incl - v;
            rowptr[i] = excl;
            cursor[i] = excl;
        }
        __syncthreads();
    }
    if (tid == 0) rowptr[N_NODES] = run;
}

// ---------------- fill CSR column list ----------------
__global__ __launch_bounds__(256) void fill_kernel(
    const int* __restrict__ src, const int* __restrict__ dst,
    int* __restrict__ cursor, int* __restrict__ col)
{
    int e = blockIdx.x * 256 + threadIdx.x;
    if (e < N_EDGES) {
        int pos = atomicAdd(&cursor[dst[e]], 1);
        col[pos] = src[e];
    }
}

// ------ z = (gather(hin) + hin) @ W1 + b1 ; accumulate BN stats --------------
__global__ __launch_bounds__(256) void gather_gemm1_kernel(
    const float* __restrict__ hin, const int* __restrict__ rowptr,
    const int* __restrict__ col, const float* __restrict__ W1,
    const float* __restrict__ b1, float* __restrict__ z,
    float* __restrict__ stats /* sum[64], sumsq[64] */)
{
    __shared__ float sW[HDIM * HDIM];
    __shared__ float sIn[4][HDIM];
    __shared__ float sRed[4][HDIM];
    int tid = threadIdx.x;
    for (int i = tid; i < HDIM * HDIM; i += 256) sW[i] = W1[i];
    int r = tid >> 6, c = tid & 63;
    float bias = b1[c];
    float s = 0.f, s2 = 0.f;
    int row0 = blockIdx.x * 64;
    __syncthreads();
    for (int it = 0; it < 16; ++it) {
        int row = row0 + it * 4 + r;
        if (row < N_NODES) {
            int e0 = rowptr[row], e1 = rowptr[row + 1];
            float a0 = 0.f, a1 = 0.f, a2 = 0.f, a3 = 0.f;
            int e = e0;
            for (; e + 4 <= e1; e += 4) {
                int c0 = col[e], c1 = col[e + 1], c2 = col[e + 2], c3 = col[e + 3];
                a0 += hin[c0 * HDIM + c];
                a1 += hin[c1 * HDIM + c];
                a2 += hin[c2 * HDIM + c];
                a3 += hin[c3 * HDIM + c];
            }
            for (; e < e1; ++e)
                a0 += hin[col[e] * HDIM + c];
            sIn[r][c] = (a0 + a1) + (a2 + a3) + hin[row * HDIM + c];
        }
        __syncthreads();
        if (row < N_NODES) {
            float acc = bias;
            #pragma unroll
            for (int k = 0; k < HDIM; ++k)
                acc = fmaf(sIn[r][k], sW[k * HDIM + c], acc);
            z[row * HDIM + c] = acc;
            s += acc;
            s2 += acc * acc;
        }
        __syncthreads();
    }
    sRed[r][c] = s;
    __syncthreads();
    if (r == 0)
        atomicAdd(&stats[c], sRed[0][c] + sRed[1][c] + sRed[2][c] + sRed[3][c]);
    __syncthreads();
    sRed[r][c] = s2;
    __syncthreads();
    if (r == 0)
        atomicAdd(&stats[HDIM + c], sRed[0][c] + sRed[1][c] + sRed[2][c] + sRed[3][c]);
}

// -------- BN finalize: scale = gamma*rsqrt(var+eps); shift = beta-mu*scale ----
__global__ void bn_finalize(const float* __restrict__ stats,
                            const float* __restrict__ gamma,
                            const float* __restrict__ beta,
                            float* __restrict__ scsh)
{
    int c = threadIdx.x;
    float mu  = stats[c] / (float)N_NODES;
    float var = stats[HDIM + c] / (float)N_NODES - mu * mu;
    float sc  = gamma[c] * rsqrtf(var + BN_EPS);
    scsh[c] = sc;
    scsh[HDIM + c] = beta[c] - mu * sc;
}

// ------- hout = relu( relu(z*scale+shift) @ W2 + b2 )  (BN applied on read) ---
__global__ __launch_bounds__(256) void gemm2_kernel(
    const float* __restrict__ z, const float* __restrict__ W2,
    const float* __restrict__ b2, const float* __restrict__ scsh,
    float* __restrict__ hout)
{
    __shared__ float sW[HDIM * HDIM];
    __shared__ float sIn[4][HDIM];
    int tid = threadIdx.x;
    for (int i = tid; i < HDIM * HDIM; i += 256) sW[i] = W2[i];
    int r = tid >> 6, c = tid & 63;
    float sc = scsh[c], sh = scsh[HDIM + c];
    float bias = b2[c];
    int row0 = blockIdx.x * 64;
    __syncthreads();
    for (int it = 0; it < 16; ++it) {
        int row = row0 + it * 4 + r;
        if (row < N_NODES) {
            float v = z[row * HDIM + c] * sc + sh;
            sIn[r][c] = v > 0.f ? v : 0.f;
        }
        __syncthreads();
        if (row < N_NODES) {
            float acc = bias;
            #pragma unroll
            for (int k = 0; k < HDIM; ++k)
                acc = fmaf(sIn[r][k], sW[k * HDIM + c], acc);
            acc = acc > 0.f ? acc : 0.f;
            hout[row * HDIM + c] = acc;
        }
        __syncthreads();
    }
}

// ---------------- segment mean pool (accumulate) ------------------------------
__global__ __launch_bounds__(256) void pool_kernel(
    const float* __restrict__ h, const int* __restrict__ batch,
    float* __restrict__ pooled, float* __restrict__ cnt)
{
    int n = blockIdx.x * 4 + (threadIdx.x >> 6);
    int c = threadIdx.x & 63;
    if (n >= N_NODES) return;
    int g = batch[n];
    atomicAdd(&pooled[g * HDIM + c], h[n * HDIM + c]);
    if (c == 0) atomicAdd(&cnt[g], 1.0f);
}

// --------------- head: relu(mean @ Wh1 + bh1) @ Wh2 + bh2 ---------------------
__global__ __launch_bounds__(64) void head_kernel(
    const float* __restrict__ pooled, const float* __restrict__ cnt,
    const float* __restrict__ Wh1, const float* __restrict__ bh1,
    const float* __restrict__ Wh2, const float* __restrict__ bh2,
    float* __restrict__ out)
{
    __shared__ float sm[HDIM];
    int g = blockIdx.x;
    int c = threadIdx.x;
    float denom = fmaxf(cnt[g], 1.0f);
    sm[c] = pooled[g * HDIM + c] / denom;
    __syncthreads();
    float acc = bh1[c];
    #pragma unroll
    for (int k = 0; k < HDIM; ++k)
        acc = fmaf(sm[k], Wh1[k * HDIM + c], acc);
    acc = fmaxf(acc, 0.f);
    float p = acc * Wh2[c];
    for (int off = 32; off > 0; off >>= 1)
        p += __shfl_down(p, off, 64);
    if (c == 0) out[g] = p + bh2[0];
}

extern "C" void kernel_launch(void* const* d_in, const int* in_sizes, int n_in,
                              void* d_out, int out_size, void* d_ws, size_t ws_size,
                              hipStream_t stream)
{
    const float* x     = (const float*)d_in[0];
    const int*   ei    = (const int*)d_in[1];
    const int*   batch = (const int*)d_in[2];
    const float* W1    = (const float*)d_in[3];
    const float* b1    = (const float*)d_in[4];
    const float* gamma = (const float*)d_in[5];
    const float* beta  = (const float*)d_in[6];
    const float* W2    = (const float*)d_in[7];
    const float* b2    = (const float*)d_in[8];
    const float* Wh1   = (const float*)d_in[9];
    const float* bh1   = (const float*)d_in[10];
    const float* Wh2   = (const float*)d_in[11];
    const float* bh2   = (const float*)d_in[12];
    float* out = (float*)d_out;

    // workspace layout
    float* ws     = (float*)d_ws;
    float* hA     = ws;                             // N*64
    float* hB     = hA + (size_t)N_NODES * HDIM;    // N*64 (z buffer)
    float* stats  = hB + (size_t)N_NODES * HDIM;    // 128
    float* scsh   = stats + 2 * HDIM;               // 128
    float* pooled = scsh + 2 * HDIM;                // 128*64
    float* cnt    = pooled + NGRAPH * HDIM;         // 128
    int*   deg    = (int*)(cnt + NGRAPH);           // N
    int*   rowptr = deg + N_NODES;                  // N+1
    int*   cursor = rowptr + N_NODES + 1;           // N
    int*   col    = cursor + N_NODES;               // E

    const int* src = ei;
    const int* dst = ei + N_EDGES;

    int gemmGrid = (N_NODES + 63) / 64;    // 782
    int edgeGrid = (N_EDGES + 255) / 256;  // 6250

    // ---- build CSR (once per call; shared by all 3 layers) ----
    hipMemsetAsync(deg, 0, N_NODES * sizeof(int), stream);
    hist_kernel<<<edgeGrid, 256, 0, stream>>>(dst, deg);
    scan_kernel<<<1, 1024, 0, stream>>>(deg, rowptr, cursor);
    fill_kernel<<<edgeGrid, 256, 0, stream>>>(src, dst, cursor, col);

    for (int l = 0; l < NLAYERS; ++l) {
        const float* hin = (l == 0) ? x : hA;
        hipMemsetAsync(stats, 0, 2 * HDIM * sizeof(float), stream);
        gather_gemm1_kernel<<<gemmGrid, 256, 0, stream>>>(
            hin, rowptr, col, W1 + l * HDIM * HDIM, b1 + l * HDIM, hB, stats);
        bn_finalize<<<1, 64, 0, stream>>>(stats, gamma + l * HDIM, beta + l * HDIM, scsh);
        gemm2_kernel<<<gemmGrid, 256, 0, stream>>>(hB, W2 + l * HDIM * HDIM,
                                                   b2 + l * HDIM, scsh, hA);
    }

    hipMemsetAsync(pooled, 0, (NGRAPH * HDIM + NGRAPH) * sizeof(float), stream);
    pool_kernel<<<(N_NODES + 3) / 4, 256, 0, stream>>>(hA, batch, pooled, cnt);
    head_kernel<<<NGRAPH, 64, 0, stream>>>(pooled, cnt, Wh1, bh1, Wh2, bh2, out);
}

// Round 3
// 767.905 us; speedup vs baseline: 2.0278x; 1.3148x over previous
//
#include <hip/hip_runtime.h>

#define N_NODES 50000
#define N_EDGES 1600000
#define HDIM 64
#define NLAYERS 3
#define NGRAPH 128
#define BN_EPS 1e-5f

// ---------------- degree histogram: deg[dst[e]]++ ----------------
__global__ __launch_bounds__(256) void hist_kernel(
    const int* __restrict__ dst, int* __restrict__ deg)
{
    int e = blockIdx.x * 256 + threadIdx.x;
    if (e < N_EDGES) atomicAdd(&deg[dst[e]], 1);
}

// ---------------- single-block exclusive scan of deg -> rowptr, cursor -------
__global__ __launch_bounds__(1024) void scan_kernel(
    const int* __restrict__ deg, int* __restrict__ rowptr, int* __restrict__ cursor)
{
    __shared__ int wsum[16];
    __shared__ int woff[17];
    int tid = threadIdx.x;
    int lane = tid & 63, wid = tid >> 6;
    int run = 0;  // persistent in tid 0's registers
    for (int base = 0; base < N_NODES; base += 1024) {
        int i = base + tid;
        int v = (i < N_NODES) ? deg[i] : 0;
        int incl = v;
        #pragma unroll
        for (int off = 1; off < 64; off <<= 1) {
            int t = __shfl_up(incl, off, 64);
            if (lane >= off) incl += t;
        }
        if (lane == 63) wsum[wid] = incl;
        __syncthreads();
        if (tid == 0) {
            int r = run;
            #pragma unroll
            for (int w = 0; w < 16; ++w) { woff[w] = r; r += wsum[w]; }
            woff[16] = r;
            run = r;
        }
        __syncthreads();
        if (i < N_NODES) {
            int excl = woff[wid] + incl - v;
            rowptr[i] = excl;
            cursor[i] = excl;
        }
        __syncthreads();
    }
    if (tid == 0) rowptr[N_NODES] = run;
}

// ---------------- fill CSR column list ----------------
__global__ __launch_bounds__(256) void fill_kernel(
    const int* __restrict__ src, const int* __restrict__ dst,
    int* __restrict__ cursor, int* __restrict__ col)
{
    int e = blockIdx.x * 256 + threadIdx.x;
    if (e < N_EDGES) {
        int pos = atomicAdd(&cursor[dst[e]], 1);
        col[pos] = src[e];
    }
}

// ------ z = (gather(hin) + hin) @ W1 + b1 ; accumulate BN stats --------------
__global__ __launch_bounds__(256) void gather_gemm1_kernel(
    const float* __restrict__ hin, const int* __restrict__ rowptr,
    const int* __restrict__ col, const float* __restrict__ W1,
    const float* __restrict__ b1, float* __restrict__ z,
    float* __restrict__ stats /* sum[64], sumsq[64] */)
{
    __shared__ float sW[HDIM * HDIM];
    __shared__ float sIn[4][HDIM];
    __shared__ float sRed[4][HDIM];
    int tid = threadIdx.x;
    for (int i = tid; i < HDIM * HDIM; i += 256) sW[i] = W1[i];
    int r = tid >> 6, c = tid & 63;
    float bias = b1[c];
    float s = 0.f, s2 = 0.f;
    int row0 = blockIdx.x * 64;
    __syncthreads();
    for (int it = 0; it < 16; ++it) {
        int row = row0 + it * 4 + r;
        if (row < N_NODES) {
            int e0 = rowptr[row], e1 = rowptr[row + 1];
            float a0 = 0.f, a1 = 0.f, a2 = 0.f, a3 = 0.f;
            int e = e0;
            for (; e + 4 <= e1; e += 4) {
                int c0 = col[e], c1 = col[e + 1], c2 = col[e + 2], c3 = col[e + 3];
                a0 += hin[c0 * HDIM + c];
                a1 += hin[c1 * HDIM + c];
                a2 += hin[c2 * HDIM + c];
                a3 += hin[c3 * HDIM + c];
            }
            for (; e < e1; ++e)
                a0 += hin[col[e] * HDIM + c];
            sIn[r][c] = (a0 + a1) + (a2 + a3) + hin[row * HDIM + c];
        }
        __syncthreads();
        if (row < N_NODES) {
            float acc = bias;
            #pragma unroll
            for (int k = 0; k < HDIM; ++k)
                acc = fmaf(sIn[r][k], sW[k * HDIM + c], acc);
            z[row * HDIM + c] = acc;
            s += acc;
            s2 += acc * acc;
        }
        __syncthreads();
    }
    sRed[r][c] = s;
    __syncthreads();
    if (r == 0)
        atomicAdd(&stats[c], sRed[0][c] + sRed[1][c] + sRed[2][c] + sRed[3][c]);
    __syncthreads();
    sRed[r][c] = s2;
    __syncthreads();
    if (r == 0)
        atomicAdd(&stats[HDIM + c], sRed[0][c] + sRed[1][c] + sRed[2][c] + sRed[3][c]);
}

// -------- BN finalize: scale = gamma*rsqrt(var+eps); shift = beta-mu*scale ----
__global__ void bn_finalize(const float* __restrict__ stats,
                            const float* __restrict__ gamma,
                            const float* __restrict__ beta,
                            float* __restrict__ scsh)
{
    int c = threadIdx.x;
    float mu  = stats[c] / (float)N_NODES;
    float var = stats[HDIM + c] / (float)N_NODES - mu * mu;
    float sc  = gamma[c] * rsqrtf(var + BN_EPS);
    scsh[c] = sc;
    scsh[HDIM + c] = beta[c] - mu * sc;
}

// ------- hout = relu( relu(z*scale+shift) @ W2 + b2 )  (BN applied on read) ---
__global__ __launch_bounds__(256) void gemm2_kernel(
    const float* __restrict__ z, const float* __restrict__ W2,
    const float* __restrict__ b2, const float* __restrict__ scsh,
    float* __restrict__ hout)
{
    __shared__ float sW[HDIM * HDIM];
    __shared__ float sIn[4][HDIM];
    int tid = threadIdx.x;
    for (int i = tid; i < HDIM * HDIM; i += 256) sW[i] = W2[i];
    int r = tid >> 6, c = tid & 63;
    float sc = scsh[c], sh = scsh[HDIM + c];
    float bias = b2[c];
    int row0 = blockIdx.x * 64;
    __syncthreads();
    for (int it = 0; it < 16; ++it) {
        int row = row0 + it * 4 + r;
        if (row < N_NODES) {
            float v = z[row * HDIM + c] * sc + sh;
            sIn[r][c] = v > 0.f ? v : 0.f;
        }
        __syncthreads();
        if (row < N_NODES) {
            float acc = bias;
            #pragma unroll
            for (int k = 0; k < HDIM; ++k)
                acc = fmaf(sIn[r][k], sW[k * HDIM + c], acc);
            acc = acc > 0.f ? acc : 0.f;
            hout[row * HDIM + c] = acc;
        }
        __syncthreads();
    }
}

// ----- graph boundary offsets from sorted batch: gstart[g] = first node of g --
__global__ __launch_bounds__(256) void bounds_kernel(
    const int* __restrict__ batch, int* __restrict__ gstart)
{
    int i = blockIdx.x * 256 + threadIdx.x;
    if (i >= N_NODES) return;
    int g1 = batch[i];
    int g0 = (i == 0) ? -1 : batch[i - 1];
    for (int g = g0 + 1; g <= g1; ++g) gstart[g] = i;
    if (i == N_NODES - 1)
        for (int g = g1 + 1; g <= NGRAPH; ++g) gstart[g] = N_NODES;
}

// ---- fused mean-pool + head: out[g] = relu(mean_g @ Wh1 + bh1) @ Wh2 + bh2 ---
__global__ __launch_bounds__(256) void pool_head_kernel(
    const float* __restrict__ h, const int* __restrict__ gstart,
    const float* __restrict__ Wh1, const float* __restrict__ bh1,
    const float* __restrict__ Wh2, const float* __restrict__ bh2,
    float* __restrict__ out)
{
    __shared__ float sW[HDIM * HDIM];
    __shared__ float sRed[4][HDIM];
    __shared__ float sMean[HDIM];
    int tid = threadIdx.x;
    int r = tid >> 6, c = tid & 63;
    int g = blockIdx.x;
    for (int i = tid; i < HDIM * HDIM; i += 256) sW[i] = Wh1[i];
    int s0 = gstart[g], s1 = gstart[g + 1];
    float acc = 0.f;
    for (int row = s0 + r; row < s1; row += 4)
        acc += h[row * HDIM + c];
    sRed[r][c] = acc;
    __syncthreads();
    if (r == 0) {
        float cntf = (float)(s1 - s0);
        sMean[c] = (sRed[0][c] + sRed[1][c] + sRed[2][c] + sRed[3][c]) /
                   fmaxf(cntf, 1.0f);
    }
    __syncthreads();
    if (r == 0) {
        float a = bh1[c];
        #pragma unroll
        for (int k = 0; k < HDIM; ++k)
            a = fmaf(sMean[k], sW[k * HDIM + c], a);
        a = fmaxf(a, 0.f);
        float p = a * Wh2[c];
        #pragma unroll
        for (int off = 32; off > 0; off >>= 1)
            p += __shfl_down(p, off, 64);
        if (c == 0) out[g] = p + bh2[0];
    }
}

extern "C" void kernel_launch(void* const* d_in, const int* in_sizes, int n_in,
                              void* d_out, int out_size, void* d_ws, size_t ws_size,
                              hipStream_t stream)
{
    const float* x     = (const float*)d_in[0];
    const int*   ei    = (const int*)d_in[1];
    const int*   batch = (const int*)d_in[2];
    const float* W1    = (const float*)d_in[3];
    const float* b1    = (const float*)d_in[4];
    const float* gamma = (const float*)d_in[5];
    const float* beta  = (const float*)d_in[6];
    const float* W2    = (const float*)d_in[7];
    const float* b2    = (const float*)d_in[8];
    const float* Wh1   = (const float*)d_in[9];
    const float* bh1   = (const float*)d_in[10];
    const float* Wh2   = (const float*)d_in[11];
    const float* bh2   = (const float*)d_in[12];
    float* out = (float*)d_out;

    // workspace layout
    float* ws     = (float*)d_ws;
    float* hA     = ws;                             // N*64
    float* hB     = hA + (size_t)N_NODES * HDIM;    // N*64 (z buffer)
    float* stats  = hB + (size_t)N_NODES * HDIM;    // 128
    float* scsh   = stats + 2 * HDIM;               // 128
    int*   gstart = (int*)(scsh + 2 * HDIM);        // NGRAPH+1
    int*   deg    = gstart + NGRAPH + 1;            // N
    int*   rowptr = deg + N_NODES;                  // N+1
    int*   cursor = rowptr + N_NODES + 1;           // N
    int*   col    = cursor + N_NODES;               // E

    const int* src = ei;
    const int* dst = ei + N_EDGES;

    int gemmGrid = (N_NODES + 63) / 64;    // 782
    int edgeGrid = (N_EDGES + 255) / 256;  // 6250
    int nodeGrid = (N_NODES + 255) / 256;  // 196

    // ---- build CSR (once per call; shared by all 3 layers) ----
    hipMemsetAsync(deg, 0, N_NODES * sizeof(int), stream);
    hist_kernel<<<edgeGrid, 256, 0, stream>>>(dst, deg);
    scan_kernel<<<1, 1024, 0, stream>>>(deg, rowptr, cursor);
    fill_kernel<<<edgeGrid, 256, 0, stream>>>(src, dst, cursor, col);
    bounds_kernel<<<nodeGrid, 256, 0, stream>>>(batch, gstart);

    for (int l = 0; l < NLAYERS; ++l) {
        const float* hin = (l == 0) ? x : hA;
        hipMemsetAsync(stats, 0, 2 * HDIM * sizeof(float), stream);
        gather_gemm1_kernel<<<gemmGrid, 256, 0, stream>>>(
            hin, rowptr, col, W1 + l * HDIM * HDIM, b1 + l * HDIM, hB, stats);
        bn_finalize<<<1, 64, 0, stream>>>(stats, gamma + l * HDIM, beta + l * HDIM, scsh);
        gemm2_kernel<<<gemmGrid, 256, 0, stream>>>(hB, W2 + l * HDIM * HDIM,
                                                   b2 + l * HDIM, scsh, hA);
    }

    pool_head_kernel<<<NGRAPH, 256, 0, stream>>>(hA, gstart, Wh1, bh1, Wh2, bh2, out);
}

// Round 4
// 726.455 us; speedup vs baseline: 2.1435x; 1.0571x over previous
//
#include <hip/hip_runtime.h>

#define N_NODES 50000
#define N_EDGES 1600000
#define HDIM 64
#define NLAYERS 3
#define NGRAPH 128
#define BN_EPS 1e-5f

// ---------------- degree histogram: deg[dst[e]]++ ----------------
__global__ __launch_bounds__(256) void hist_kernel(
    const int* __restrict__ dst, int* __restrict__ deg)
{
    int e = blockIdx.x * 256 + threadIdx.x;
    if (e < N_EDGES) atomicAdd(&deg[dst[e]], 1);
}

// ---------------- single-block exclusive scan of deg -> rowptr, cursor -------
__global__ __launch_bounds__(1024) void scan_kernel(
    const int* __restrict__ deg, int* __restrict__ rowptr, int* __restrict__ cursor)
{
    __shared__ int wsum[16];
    __shared__ int woff[17];
    int tid = threadIdx.x;
    int lane = tid & 63, wid = tid >> 6;
    int run = 0;  // persistent in tid 0's registers
    for (int base = 0; base < N_NODES; base += 1024) {
        int i = base + tid;
        int v = (i < N_NODES) ? deg[i] : 0;
        int incl = v;
        #pragma unroll
        for (int off = 1; off < 64; off <<= 1) {
            int t = __shfl_up(incl, off, 64);
            if (lane >= off) incl += t;
        }
        if (lane == 63) wsum[wid] = incl;
        __syncthreads();
        if (tid == 0) {
            int r = run;
            #pragma unroll
            for (int w = 0; w < 16; ++w) { woff[w] = r; r += wsum[w]; }
            woff[16] = r;
            run = r;
        }
        __syncthreads();
        if (i < N_NODES) {
            int excl = woff[wid] + incl - v;
            rowptr[i] = excl;
            cursor[i] = excl;
        }
        __syncthreads();
    }
    if (tid == 0) rowptr[N_NODES] = run;
}

// ---------------- fill CSR column list ----------------
__global__ __launch_bounds__(256) void fill_kernel(
    const int* __restrict__ src, const int* __restrict__ dst,
    int* __restrict__ cursor, int* __restrict__ col)
{
    int e = blockIdx.x * 256 + threadIdx.x;
    if (e < N_EDGES) {
        int pos = atomicAdd(&cursor[dst[e]], 1);
        col[pos] = src[e];
    }
}

// ------ z = (gather(hin) + hin) @ W1 + b1 ; accumulate BN stats --------------
// One wave per row; 4 edges gathered per float4 load instruction.
// N_NODES % 16 == 0 so no bounds checks.
__global__ __launch_bounds__(256) void gather_gemm1_kernel(
    const float* __restrict__ hin, const int* __restrict__ rowptr,
    const int* __restrict__ col, const float* __restrict__ W1,
    const float* __restrict__ b1, float* __restrict__ z,
    float* __restrict__ stats /* sum[64], sumsq[64] */)
{
    __shared__ float sW[HDIM * HDIM];
    __shared__ float sIn[4][HDIM];
    __shared__ float sRed[4][HDIM];
    const float4* hin4 = (const float4*)hin;
    int tid = threadIdx.x;
    for (int i = tid; i < HDIM * HDIM; i += 256) sW[i] = W1[i];
    int r = tid >> 6;      // wave id (row slot)
    int c = tid & 63;      // lane
    int sub = c >> 4;      // edge slot 0..3
    int q = c & 15;        // float4 slot: channels q*4 .. q*4+3
    float bias = b1[c];
    float s = 0.f, s2 = 0.f;
    int row0 = blockIdx.x * 16;
    __syncthreads();
    for (int it = 0; it < 4; ++it) {
        int row = row0 + it * 4 + r;
        int e0 = rowptr[row], e1 = rowptr[row + 1];
        float ax = 0.f, ay = 0.f, az = 0.f, aw = 0.f;
        int e = e0;
        for (; e + 8 <= e1; e += 8) {
            int c0 = col[e + sub];
            int c1 = col[e + 4 + sub];
            float4 v0 = hin4[(size_t)c0 * 16 + q];
            float4 v1 = hin4[(size_t)c1 * 16 + q];
            ax += v0.x + v1.x; ay += v0.y + v1.y;
            az += v0.z + v1.z; aw += v0.w + v1.w;
        }
        if (e + 4 <= e1) {
            int c0 = col[e + sub];
            float4 v0 = hin4[(size_t)c0 * 16 + q];
            ax += v0.x; ay += v0.y; az += v0.z; aw += v0.w;
            e += 4;
        }
        int rem = e1 - e;
        if (sub < rem) {
            int c0 = col[e + sub];
            float4 v0 = hin4[(size_t)c0 * 16 + q];
            ax += v0.x; ay += v0.y; az += v0.z; aw += v0.w;
        }
        // reduce the 4 edge slots (xor 16, then 32)
        ax += __shfl_xor(ax, 16, 64); ay += __shfl_xor(ay, 16, 64);
        az += __shfl_xor(az, 16, 64); aw += __shfl_xor(aw, 16, 64);
        ax += __shfl_xor(ax, 32, 64); ay += __shfl_xor(ay, 32, 64);
        az += __shfl_xor(az, 32, 64); aw += __shfl_xor(aw, 32, 64);
        // + self row ((1+eps)*x with eps=0)
        float4 sv = hin4[(size_t)row * 16 + q];
        ax += sv.x; ay += sv.y; az += sv.z; aw += sv.w;
        if (sub == 0) {
            float4 o; o.x = ax; o.y = ay; o.z = az; o.w = aw;
            *(float4*)&sIn[r][q * 4] = o;
        }
        __syncthreads();
        float acc = bias;
        #pragma unroll
        for (int k = 0; k < HDIM; ++k)
            acc = fmaf(sIn[r][k], sW[k * HDIM + c], acc);
        z[row * HDIM + c] = acc;
        s += acc;
        s2 += acc * acc;
        __syncthreads();
    }
    sRed[r][c] = s;
    __syncthreads();
    if (r == 0)
        atomicAdd(&stats[c], sRed[0][c] + sRed[1][c] + sRed[2][c] + sRed[3][c]);
    __syncthreads();
    sRed[r][c] = s2;
    __syncthreads();
    if (r == 0)
        atomicAdd(&stats[HDIM + c], sRed[0][c] + sRed[1][c] + sRed[2][c] + sRed[3][c]);
}

// -------- BN finalize: scale = gamma*rsqrt(var+eps); shift = beta-mu*scale ----
__global__ void bn_finalize(const float* __restrict__ stats,
                            const float* __restrict__ gamma,
                            const float* __restrict__ beta,
                            float* __restrict__ scsh)
{
    int c = threadIdx.x;
    float mu  = stats[c] / (float)N_NODES;
    float var = stats[HDIM + c] / (float)N_NODES - mu * mu;
    float sc  = gamma[c] * rsqrtf(var + BN_EPS);
    scsh[c] = sc;
    scsh[HDIM + c] = beta[c] - mu * sc;
}

// ------- hout = relu( relu(z*scale+shift) @ W2 + b2 )  (BN applied on read) ---
__global__ __launch_bounds__(256) void gemm2_kernel(
    const float* __restrict__ z, const float* __restrict__ W2,
    const float* __restrict__ b2, const float* __restrict__ scsh,
    float* __restrict__ hout)
{
    __shared__ float sW[HDIM * HDIM];
    __shared__ float sIn[4][HDIM];
    int tid = threadIdx.x;
    for (int i = tid; i < HDIM * HDIM; i += 256) sW[i] = W2[i];
    int r = tid >> 6, c = tid & 63;
    float sc = scsh[c], sh = scsh[HDIM + c];
    float bias = b2[c];
    int row0 = blockIdx.x * 16;
    __syncthreads();
    for (int it = 0; it < 4; ++it) {
        int row = row0 + it * 4 + r;
        float v = z[row * HDIM + c] * sc + sh;
        sIn[r][c] = v > 0.f ? v : 0.f;
        __syncthreads();
        float acc = bias;
        #pragma unroll
        for (int k = 0; k < HDIM; ++k)
            acc = fmaf(sIn[r][k], sW[k * HDIM + c], acc);
        acc = acc > 0.f ? acc : 0.f;
        hout[row * HDIM + c] = acc;
        __syncthreads();
    }
}

// ----- graph boundary offsets from sorted batch: gstart[g] = first node of g --
__global__ __launch_bounds__(256) void bounds_kernel(
    const int* __restrict__ batch, int* __restrict__ gstart)
{
    int i = blockIdx.x * 256 + threadIdx.x;
    if (i >= N_NODES) return;
    int g1 = batch[i];
    int g0 = (i == 0) ? -1 : batch[i - 1];
    for (int g = g0 + 1; g <= g1; ++g) gstart[g] = i;
    if (i == N_NODES - 1)
        for (int g = g1 + 1; g <= NGRAPH; ++g) gstart[g] = N_NODES;
}

// ---- fused mean-pool + head: out[g] = relu(mean_g @ Wh1 + bh1) @ Wh2 + bh2 ---
__global__ __launch_bounds__(256) void pool_head_kernel(
    const float* __restrict__ h, const int* __restrict__ gstart,
    const float* __restrict__ Wh1, const float* __restrict__ bh1,
    const float* __restrict__ Wh2, const float* __restrict__ bh2,
    float* __restrict__ out)
{
    __shared__ float sW[HDIM * HDIM];
    __shared__ float sRed[4][HDIM];
    __shared__ float sMean[HDIM];
    int tid = threadIdx.x;
    int r = tid >> 6, c = tid & 63;
    int g = blockIdx.x;
    for (int i = tid; i < HDIM * HDIM; i += 256) sW[i] = Wh1[i];
    int s0 = gstart[g], s1 = gstart[g + 1];
    float acc = 0.f;
    for (int row = s0 + r; row < s1; row += 4)
        acc += h[row * HDIM + c];
    sRed[r][c] = acc;
    __syncthreads();
    if (r == 0) {
        float cntf = (float)(s1 - s0);
        sMean[c] = (sRed[0][c] + sRed[1][c] + sRed[2][c] + sRed[3][c]) /
                   fmaxf(cntf, 1.0f);
    }
    __syncthreads();
    if (r == 0) {
        float a = bh1[c];
        #pragma unroll
        for (int k = 0; k < HDIM; ++k)
            a = fmaf(sMean[k], sW[k * HDIM + c], a);
        a = fmaxf(a, 0.f);
        float p = a * Wh2[c];
        #pragma unroll
        for (int off = 32; off > 0; off >>= 1)
            p += __shfl_down(p, off, 64);
        if (c == 0) out[g] = p + bh2[0];
    }
}

extern "C" void kernel_launch(void* const* d_in, const int* in_sizes, int n_in,
                              void* d_out, int out_size, void* d_ws, size_t ws_size,
                              hipStream_t stream)
{
    const float* x     = (const float*)d_in[0];
    const int*   ei    = (const int*)d_in[1];
    const int*   batch = (const int*)d_in[2];
    const float* W1    = (const float*)d_in[3];
    const float* b1    = (const float*)d_in[4];
    const float* gamma = (const float*)d_in[5];
    const float* beta  = (const float*)d_in[6];
    const float* W2    = (const float*)d_in[7];
    const float* b2    = (const float*)d_in[8];
    const float* Wh1   = (const float*)d_in[9];
    const float* bh1   = (const float*)d_in[10];
    const float* Wh2   = (const float*)d_in[11];
    const float* bh2   = (const float*)d_in[12];
    float* out = (float*)d_out;

    // workspace layout
    float* ws     = (float*)d_ws;
    float* hA     = ws;                             // N*64
    float* hB     = hA + (size_t)N_NODES * HDIM;    // N*64 (z buffer)
    float* stats  = hB + (size_t)N_NODES * HDIM;    // 128
    float* scsh   = stats + 2 * HDIM;               // 128
    int*   gstart = (int*)(scsh + 2 * HDIM);        // NGRAPH+1
    int*   deg    = gstart + NGRAPH + 1;            // N
    int*   rowptr = deg + N_NODES;                  // N+1
    int*   cursor = rowptr + N_NODES + 1;           // N
    int*   col    = cursor + N_NODES;               // E

    const int* src = ei;
    const int* dst = ei + N_EDGES;

    int tileGrid = N_NODES / 16;           // 3125 (exact)
    int edgeGrid = (N_EDGES + 255) / 256;  // 6250
    int nodeGrid = (N_NODES + 255) / 256;  // 196

    // ---- build CSR (once per call; shared by all 3 layers) ----
    hipMemsetAsync(deg, 0, N_NODES * sizeof(int), stream);
    hist_kernel<<<edgeGrid, 256, 0, stream>>>(dst, deg);
    scan_kernel<<<1, 1024, 0, stream>>>(deg, rowptr, cursor);
    fill_kernel<<<edgeGrid, 256, 0, stream>>>(src, dst, cursor, col);
    bounds_kernel<<<nodeGrid, 256, 0, stream>>>(batch, gstart);

    for (int l = 0; l < NLAYERS; ++l) {
        const float* hin = (l == 0) ? x : hA;
        hipMemsetAsync(stats, 0, 2 * HDIM * sizeof(float), stream);
        gather_gemm1_kernel<<<tileGrid, 256, 0, stream>>>(
            hin, rowptr, col, W1 + l * HDIM * HDIM, b1 + l * HDIM, hB, stats);
        bn_finalize<<<1, 64, 0, stream>>>(stats, gamma + l * HDIM, beta + l * HDIM, scsh);
        gemm2_kernel<<<tileGrid, 256, 0, stream>>>(hB, W2 + l * HDIM * HDIM,
                                                   b2 + l * HDIM, scsh, hA);
    }

    pool_head_kernel<<<NGRAPH, 256, 0, stream>>>(hA, gstart, Wh1, bh1, Wh2, bh2, out);
}